// Round 6
// baseline (45.699 us; speedup 1.0000x reference)
//
#include <hip/hip_runtime.h>

// Problem constants (fixed by setup_inputs): B=8, L=16384, H=2, BLOCK=128, VOCAB=32000
#define NB        8
#define LLEN      16384
#define NHEAD     2
#define BLOCKSZ   128
#define VOCAB     32000
#define NBLK      (LLEN / BLOCKSZ)                  // 128
#define NCHUNK    (NB * NBLK)                       // 1024
#define TOKS_PER_CHUNK (BLOCKSZ * NHEAD)            // 256
#define NT_COLS   (TOKS_PER_CHUNK + LLEN * NHEAD)   // 33024 per batch row
#define NT_TOTAL  (NB * NT_COLS)                    // 264192
#define CAT_TOTAL (NB * TOKS_PER_CHUNK)             // 2048
#define HIST_OFF  (NT_TOTAL + CAT_TOTAL)            // 266240
#define NF4       (VOCAB / 4)                       // 8000 f4 slots per row
#define MAXH      8                                 // register hit-list capacity

typedef float f32x4 __attribute__((ext_vector_type(4)));

// One workgroup per (b,n) chunk. Thread t owns f4 slots g = t + 256k, k<32
// (k=31 only exists for t<64). Each f4 is written EXACTLY ONCE with its final
// value: burst writes zeros to non-hit slots (predicated), then the <=MAXH
// hit slots get merged count-f4s. No vmcnt fence, no rewrites, no atomics.
__global__ __launch_bounds__(256) void fused_kernel(const int* __restrict__ tokens,
                                                    float* __restrict__ out) {
    __shared__ int toks[TOKS_PER_CHUNK];
    __shared__ int ovf;

    const int tid = threadIdx.x;
    const int chunk = blockIdx.x;                 // b*128 + n
    const int b = chunk >> 7;
    const int n = chunk & 127;

    const int v = tokens[(size_t)chunk * TOKS_PER_CHUNK + tid];
    toks[tid] = v;
    if (tid == 0) ovf = 0;
    __syncthreads();

    // scan: which of MY 32 f4 slots are hit, and by which token positions.
    // owner thread of value u is (u>>2)&255; its k-slot is u>>10.
    unsigned kmask = 0; unsigned jp0 = 0, jp1 = 0; int nh = 0;
    #pragma unroll 8
    for (int j = 0; j < TOKS_PER_CHUNK; ++j) {
        const int u = toks[j];                    // broadcast read, conflict-free
        if (((u >> 2) & 255) == tid) {
            kmask |= 1u << (u >> 10);
            jp1 = (jp1 << 8) | (jp0 >> 24);
            jp0 = (jp0 << 8) | (unsigned)j;
            ++nh;
        }
    }
    if (nh > MAXH) ovf = 1;
    __syncthreads();                              // cheap (lgkm only)

    float* __restrict__ row = out + (size_t)HIST_OFF + (size_t)chunk * VOCAB;
    f32x4* __restrict__ row4 = reinterpret_cast<f32x4*>(row);
    const f32x4 z = {0.f, 0.f, 0.f, 0.f};

    if (!ovf) {
        // ---- zero burst, skipping hit slots (predicated stores) ----
        #pragma unroll
        for (int k = 0; k < 31; ++k)
            if (!((kmask >> k) & 1u)) row4[tid + (k << 8)] = z;
        if (tid < 64 && !((kmask >> 31) & 1u)) row4[7936 + tid] = z;

        // ---- merged count-f4s for hit slots (avg 1 per thread) ----
        const unsigned long long jp = ((unsigned long long)jp1 << 32) | jp0;
        unsigned m = kmask;
        while (m) {
            const int k = __ffs(m) - 1; m &= m - 1;
            f32x4 f = z;
            for (int h = 0; h < nh; ++h) {
                const int jh = (int)((jp >> (8 * h)) & 255u);
                const int u = toks[jh];
                if ((u >> 10) == k) {
                    int c = 0;
                    for (int h2 = 0; h2 < nh; ++h2) {
                        const int j2 = (int)((jp >> (8 * h2)) & 255u);
                        c += (toks[j2] == u);
                    }
                    f[u & 3] = (float)c;          // dups rewrite same value
                }
            }
            row4[tid + (k << 8)] = f;
        }
    } else {
        // Fallback (any-data correctness): zero all, drain, scan, scatter.
        #pragma unroll
        for (int k = 0; k < 31; ++k) row4[tid + (k << 8)] = z;
        if (tid < 64) row4[7936 + tid] = z;
        __syncthreads();
        int c = 0, first = -1;
        for (int j = 0; j < TOKS_PER_CHUNK; ++j) {
            const int u = toks[j];
            c += (u == v);
            if (u == v && first < 0) first = j;
        }
        if (first == tid) row[v] = (float)c;
    }

    // token outputs (tiny; off the burst's critical path)
    const float fv = (float)v;
    out[(size_t)b * NT_COLS + TOKS_PER_CHUNK + n * TOKS_PER_CHUNK + tid] = fv;
    if (tid < NHEAD) {
        out[(size_t)b * NT_COLS + n * NHEAD + tid] = fv;                    // new_tokens cat part
        out[(size_t)NT_TOTAL + b * TOKS_PER_CHUNK + n * NHEAD + tid] = fv;  // cat_ids
    }
}

extern "C" void kernel_launch(void* const* d_in, const int* in_sizes, int n_in,
                              void* d_out, int out_size, void* d_ws, size_t ws_size,
                              hipStream_t stream) {
    const int* tokens = (const int*)d_in[0];
    float* out = (float*)d_out;
    fused_kernel<<<NCHUNK, 256, 0, stream>>>(tokens, out);
}

// Round 7
// 28.016 us; speedup vs baseline: 1.6312x; 1.6312x over previous
//
#include <hip/hip_runtime.h>

// Problem constants (fixed by setup_inputs): B=8, L=16384, H=2, BLOCK=128, VOCAB=32000
#define NB        8
#define LLEN      16384
#define NHEAD     2
#define BLOCKSZ   128
#define VOCAB     32000
#define NBLK      (LLEN / BLOCKSZ)                  // 128
#define NCHUNK    (NB * NBLK)                       // 1024
#define TOKS_PER_CHUNK (BLOCKSZ * NHEAD)            // 256
#define NT_COLS   (TOKS_PER_CHUNK + LLEN * NHEAD)   // 33024 per batch row
#define NT_TOTAL  (NB * NT_COLS)                    // 264192
#define CAT_TOTAL (NB * TOKS_PER_CHUNK)             // 2048
#define HIST_OFF  (NT_TOTAL + CAT_TOTAL)            // 266240
#define NF4       (VOCAB / 4)                       // 8000 f4 slots per row
#define CAP       16                                // bucket capacity (overflow -> fallback)
#define CAPP      17                                // padded stride (kills LDS bank conflicts)

typedef float f32x4 __attribute__((ext_vector_type(4)));

// One workgroup per (b,n) chunk. Thread t owns f4 slots g = t + 256k.
// Order: [issue token load] -> [31/32 unconditional f4 zero stores] ->
// [token outs] -> [LDS bucketing under the store drain, lgkm-only barriers] ->
// [one vmcnt(0)] -> [rewrite hit slots with counts].
__global__ __launch_bounds__(256) void fused_kernel(const int* __restrict__ tokens,
                                                    float* __restrict__ out) {
    __shared__ int toks[TOKS_PER_CHUNK];
    __shared__ unsigned bcnt[256];
    __shared__ int bval[256][CAPP];
    __shared__ int ovf;

    const int tid = threadIdx.x;
    const int chunk = blockIdx.x;                 // b*128 + n
    const int b = chunk >> 7;
    const int n = chunk & 127;

    // issue the token load FIRST; it retires under the burst (vmcnt in-order)
    const int v = tokens[(size_t)chunk * TOKS_PER_CHUNK + tid];

    // ---- zero burst: branch-free, no dependencies, starts immediately ----
    float* __restrict__ row = out + (size_t)HIST_OFF + (size_t)chunk * VOCAB;
    f32x4* __restrict__ row4 = reinterpret_cast<f32x4*>(row);
    const f32x4 z = {0.f, 0.f, 0.f, 0.f};
    #pragma unroll
    for (int k = 0; k < 31; ++k)                  // 31*256 = 7936 f4s
        row4[tid + (k << 8)] = z;
    if (tid < 64) row4[7936 + tid] = z;           // tail 64 f4s

    // ---- token outputs (wait only on the load, not the stores) ----
    const float fv = (float)v;
    out[(size_t)b * NT_COLS + TOKS_PER_CHUNK + n * TOKS_PER_CHUNK + tid] = fv;
    if (tid < NHEAD) {
        out[(size_t)b * NT_COLS + n * NHEAD + tid] = fv;                    // new_tokens cat part
        out[(size_t)NT_TOTAL + b * TOKS_PER_CHUNK + n * NHEAD + tid] = fv;  // cat_ids
    }

    // ---- bucketing, overlapped with the global-store drain ----
    toks[tid] = v;
    bcnt[tid] = 0;
    if (tid == 0) ovf = 0;
    asm volatile("s_waitcnt lgkmcnt(0)" ::: "memory");   // LDS visible; do NOT drain vmcnt
    __builtin_amdgcn_s_barrier();

    {   // owner thread of value v is (v>>2)&255
        const int o = (v >> 2) & 255;
        unsigned slot = atomicAdd(&bcnt[o], 1u);
        if (slot < CAP) bval[o][slot] = v;
        else ovf = 1;                              // racy same-value store, read after barrier
    }
    asm volatile("s_waitcnt lgkmcnt(0)" ::: "memory");
    __builtin_amdgcn_s_barrier();

    if (!ovf) {
        // my zero stores must be retired before my same-address rewrites
        asm volatile("s_waitcnt vmcnt(0)" ::: "memory");

        const int n_e = (int)bcnt[tid];            // <= CAP here
        for (int e = 0; e < n_e; ++e) {
            const int ve = bval[tid][e];
            int c = 0; bool first = true;
            for (int e2 = 0; e2 < n_e; ++e2) {
                const int u = bval[tid][e2];
                c += (u == ve);
                if (u == ve && e2 < e) first = false;
            }
            if (first) row[ve] = (float)c;         // disjoint bytes; line L2-dirty
        }
    } else {
        // Fallback (any-data correctness): full drain, scan, scatter.
        __syncthreads();                           // vmcnt(0)+lgkmcnt(0)+barrier
        int c = 0, first = -1;
        for (int j = 0; j < TOKS_PER_CHUNK; ++j) {
            const int u = toks[j];
            c += (u == v);
            if (u == v && first < 0) first = j;
        }
        if (first == tid) row[v] = (float)c;
    }
}

extern "C" void kernel_launch(void* const* d_in, const int* in_sizes, int n_in,
                              void* d_out, int out_size, void* d_ws, size_t ws_size,
                              hipStream_t stream) {
    const int* tokens = (const int*)d_in[0];
    float* out = (float*)d_out;
    fused_kernel<<<NCHUNK, 256, 0, stream>>>(tokens, out);
}

// Round 8
// 25.764 us; speedup vs baseline: 1.7737x; 1.0874x over previous
//
#include <hip/hip_runtime.h>

// Problem constants (fixed by setup_inputs): B=8, L=16384, H=2, BLOCK=128, VOCAB=32000
#define NB        8
#define LLEN      16384
#define NHEAD     2
#define BLOCKSZ   128
#define VOCAB     32000
#define NBLK      (LLEN / BLOCKSZ)                  // 128
#define NCHUNK    (NB * NBLK)                       // 1024
#define TOKS_PER_CHUNK (BLOCKSZ * NHEAD)            // 256
#define NT_COLS   (TOKS_PER_CHUNK + LLEN * NHEAD)   // 33024 per batch row
#define NT_TOTAL  (NB * NT_COLS)                    // 264192
#define CAT_TOTAL (NB * TOKS_PER_CHUNK)             // 2048
#define HIST_OFF  (NT_TOTAL + CAT_TOTAL)            // 266240
#define NF4       (VOCAB / 4)                       // 8000 f4 slots per row
#define QF4       (NF4 / 4)                         // 2000 f4 slots per quarter
#define KFULL     7                                 // 7*256 = 1792 full stores/thread
#define QTAIL     (QF4 - KFULL * 256)               // 208 tail f4s (threads t<208)
#define CAP       16                                // bucket capacity (overflow -> fallback)
#define CAPP      17                                // padded stride (kills LDS bank conflicts)

typedef float f32x4 __attribute__((ext_vector_type(4)));

// 4096 blocks: one per (chunk, quarter). Thread t owns quarter-local f4 slots
// g_local = t + 256k (k<7) plus tail 1792+t (t<208). Burst zeros first (no deps),
// bucket under the drain, one vmcnt(0), rewrite owned hit slots with counts.
// 8 blocks/CU resident -> 2 dispatch rounds pipeline prologue/drain phases.
__global__ __launch_bounds__(256) void fused_kernel(const int* __restrict__ tokens,
                                                    float* __restrict__ out) {
    __shared__ int toks[TOKS_PER_CHUNK];
    __shared__ unsigned bcnt[256];
    __shared__ int bval[256][CAPP];
    __shared__ int ovf;

    const int tid = threadIdx.x;
    const int chunk = blockIdx.x >> 2;            // b*128 + n
    const int q = blockIdx.x & 3;                 // vocab quarter
    const int b = chunk >> 7;
    const int n = chunk & 127;

    // issue token load first; it retires under the burst (vmcnt in-order)
    const int v = tokens[(size_t)chunk * TOKS_PER_CHUNK + tid];

    // ---- zero burst: branch-free, starts immediately ----
    float* __restrict__ row = out + (size_t)HIST_OFF + (size_t)chunk * VOCAB;
    f32x4* __restrict__ row4 = reinterpret_cast<f32x4*>(row) + q * QF4;
    const f32x4 z = {0.f, 0.f, 0.f, 0.f};
    #pragma unroll
    for (int k = 0; k < KFULL; ++k)               // 7*256 = 1792 f4s
        row4[tid + (k << 8)] = z;
    if (tid < QTAIL) row4[KFULL * 256 + tid] = z; // tail 208 f4s

    // ---- token outputs (only quarter-0 blocks) ----
    if (q == 0) {
        const float fv = (float)v;
        out[(size_t)b * NT_COLS + TOKS_PER_CHUNK + n * TOKS_PER_CHUNK + tid] = fv;
        if (tid < NHEAD) {
            out[(size_t)b * NT_COLS + n * NHEAD + tid] = fv;                    // new_tokens cat
            out[(size_t)NT_TOTAL + b * TOKS_PER_CHUNK + n * NHEAD + tid] = fv;  // cat_ids
        }
    }

    // ---- bucketing, overlapped with the global-store drain ----
    toks[tid] = v;
    bcnt[tid] = 0;
    if (tid == 0) ovf = 0;
    asm volatile("s_waitcnt lgkmcnt(0)" ::: "memory");   // LDS visible; do NOT drain vmcnt
    __builtin_amdgcn_s_barrier();

    {   // push v to its owner thread if it falls in this block's quarter
        const unsigned gl = (unsigned)(v >> 2) - (unsigned)(q * QF4);
        if (gl < QF4) {
            const int o = gl & 255;
            unsigned slot = atomicAdd(&bcnt[o], 1u);
            if (slot < CAP) bval[o][slot] = v;
            else ovf = 1;                          // racy same-value store, read after barrier
        }
    }
    asm volatile("s_waitcnt lgkmcnt(0)" ::: "memory");
    __builtin_amdgcn_s_barrier();

    if (!ovf) {
        // my zero stores must be retired before my same-address rewrites
        asm volatile("s_waitcnt vmcnt(0)" ::: "memory");

        const int n_e = (int)bcnt[tid];            // <= CAP here
        for (int e = 0; e < n_e; ++e) {
            const int ve = bval[tid][e];
            int c = 0; bool first = true;
            for (int e2 = 0; e2 < n_e; ++e2) {
                const int u = bval[tid][e2];
                c += (u == ve);
                if (u == ve && e2 < e) first = false;
            }
            if (first) row[ve] = (float)c;         // disjoint bytes; line L2-dirty
        }
    } else {
        // Fallback (any-data correctness): full drain, scan, scatter within quarter.
        __syncthreads();                           // vmcnt(0)+lgkmcnt(0)+barrier
        int c = 0, first = -1;
        for (int j = 0; j < TOKS_PER_CHUNK; ++j) {
            const int u = toks[j];
            c += (u == v);
            if (u == v && first < 0) first = j;
        }
        const unsigned gl = (unsigned)(v >> 2) - (unsigned)(q * QF4);
        if (first == tid && gl < QF4) row[v] = (float)c;
    }
}

extern "C" void kernel_launch(void* const* d_in, const int* in_sizes, int n_in,
                              void* d_out, int out_size, void* d_ws, size_t ws_size,
                              hipStream_t stream) {
    const int* tokens = (const int*)d_in[0];
    float* out = (float*)d_out;
    fused_kernel<<<NCHUNK * 4, 256, 0, stream>>>(tokens, out);
}

// Round 9
// 25.459 us; speedup vs baseline: 1.7950x; 1.0120x over previous
//
#include <hip/hip_runtime.h>

// Problem constants (fixed by setup_inputs): B=8, L=16384, H=2, BLOCK=128, VOCAB=32000
#define NB        8
#define LLEN      16384
#define NHEAD     2
#define BLOCKSZ   128
#define VOCAB     32000
#define NBLK      (LLEN / BLOCKSZ)                  // 128
#define NCHUNK    (NB * NBLK)                       // 1024
#define TOKS_PER_CHUNK (BLOCKSZ * NHEAD)            // 256
#define NT_COLS   (TOKS_PER_CHUNK + LLEN * NHEAD)   // 33024 per batch row
#define NT_TOTAL  (NB * NT_COLS)                    // 264192
#define CAT_TOTAL (NB * TOKS_PER_CHUNK)             // 2048
#define HIST_OFF  (NT_TOTAL + CAT_TOTAL)            // 266240
#define NF4       (VOCAB / 4)                       // 8000 f4 slots per row
#define NSPLIT    8
#define QF4       (NF4 / NSPLIT)                    // 1000 f4 slots per eighth
#define KFULL     3                                 // 3*256 = 768 full stores/thread
#define QTAIL     (QF4 - KFULL * 256)               // 232 tail f4s (threads t<232)
#define CAP       16                                // bucket capacity (overflow -> fallback)
#define CAPP      17                                // padded stride (kills LDS bank conflicts)

typedef float f32x4 __attribute__((ext_vector_type(4)));

// 8192 blocks: one per (chunk, eighth). Thread t owns eighth-local f4 slots
// {t, t+256, t+512} plus {768+t | t<232}. Burst zeros first (no deps), bucket
// under the store drain, one vmcnt(0), rewrite owned hit slots with counts.
// 8 blocks/CU resident, 4 dispatch rounds -> deep phase pipelining.
__global__ __launch_bounds__(256) void fused_kernel(const int* __restrict__ tokens,
                                                    float* __restrict__ out) {
    __shared__ int toks[TOKS_PER_CHUNK];
    __shared__ unsigned bcnt[256];
    __shared__ int bval[256][CAPP];
    __shared__ int ovf;

    const int tid = threadIdx.x;
    const int chunk = blockIdx.x >> 3;            // b*128 + n
    const int q = blockIdx.x & 7;                 // vocab eighth
    const int b = chunk >> 7;
    const int n = chunk & 127;

    // issue token load first; it retires under the burst (vmcnt in-order)
    const int v = tokens[(size_t)chunk * TOKS_PER_CHUNK + tid];

    // ---- zero burst: branch-free, starts immediately ----
    float* __restrict__ row = out + (size_t)HIST_OFF + (size_t)chunk * VOCAB;
    f32x4* __restrict__ row4 = reinterpret_cast<f32x4*>(row) + q * QF4;
    const f32x4 z = {0.f, 0.f, 0.f, 0.f};
    #pragma unroll
    for (int k = 0; k < KFULL; ++k)               // 768 f4s
        row4[tid + (k << 8)] = z;
    if (tid < QTAIL) row4[KFULL * 256 + tid] = z; // tail 232 f4s

    // ---- token outputs (only eighth-0 blocks) ----
    if (q == 0) {
        const float fv = (float)v;
        out[(size_t)b * NT_COLS + TOKS_PER_CHUNK + n * TOKS_PER_CHUNK + tid] = fv;
        if (tid < NHEAD) {
            out[(size_t)b * NT_COLS + n * NHEAD + tid] = fv;                    // new_tokens cat
            out[(size_t)NT_TOTAL + b * TOKS_PER_CHUNK + n * NHEAD + tid] = fv;  // cat_ids
        }
    }

    // ---- bucketing, overlapped with the global-store drain ----
    toks[tid] = v;
    bcnt[tid] = 0;
    if (tid == 0) ovf = 0;
    asm volatile("s_waitcnt lgkmcnt(0)" ::: "memory");   // LDS visible; do NOT drain vmcnt
    __builtin_amdgcn_s_barrier();

    {   // push v to its owner thread if it falls in this block's eighth
        const unsigned gl = (unsigned)(v >> 2) - (unsigned)(q * QF4);
        if (gl < QF4) {
            const int o = (int)(gl & 255u);        // consistent with slot ownership
            unsigned slot = atomicAdd(&bcnt[o], 1u);
            if (slot < CAP) bval[o][slot] = v;
            else ovf = 1;                          // racy same-value store, read after barrier
        }
    }
    asm volatile("s_waitcnt lgkmcnt(0)" ::: "memory");
    __builtin_amdgcn_s_barrier();

    if (!ovf) {
        // my zero stores must be retired before my same-address rewrites
        asm volatile("s_waitcnt vmcnt(0)" ::: "memory");

        const int n_e = (int)bcnt[tid];            // <= CAP here
        for (int e = 0; e < n_e; ++e) {
            const int ve = bval[tid][e];
            int c = 0; bool first = true;
            for (int e2 = 0; e2 < n_e; ++e2) {
                const int u = bval[tid][e2];
                c += (u == ve);
                if (u == ve && e2 < e) first = false;
            }
            if (first) row[ve] = (float)c;         // disjoint bytes; line L2-dirty
        }
    } else {
        // Fallback (any-data correctness): full drain, scan, scatter within eighth.
        __syncthreads();                           // vmcnt(0)+lgkmcnt(0)+barrier
        int c = 0, first = -1;
        for (int j = 0; j < TOKS_PER_CHUNK; ++j) {
            const int u = toks[j];
            c += (u == v);
            if (u == v && first < 0) first = j;
        }
        const unsigned gl = (unsigned)(v >> 2) - (unsigned)(q * QF4);
        if (first == tid && gl < QF4) row[v] = (float)c;
    }
}

extern "C" void kernel_launch(void* const* d_in, const int* in_sizes, int n_in,
                              void* d_out, int out_size, void* d_ws, size_t ws_size,
                              hipStream_t stream) {
    const int* tokens = (const int*)d_in[0];
    float* out = (float*)d_out;
    fused_kernel<<<NCHUNK * NSPLIT, 256, 0, stream>>>(tokens, out);
}